// Round 10
// baseline (1369.307 us; speedup 1.0000x reference)
//
#include <hip/hip_runtime.h>

// ---------------- problem constants ----------------
constexpr int B_ = 2, N_ = 512, SEL_ = 128, T_ = 4, P_ = 16;
constexpr int F2_ = 128, H_ = 256, DIN_ = 2048;
constexpr int NBT_ = B_ * N_ * SEL_;   // 131072 neighbors
constexpr int NA_  = B_ * N_;          // 1024 atoms
constexpr int NBLK_ = NBT_ / 256;      // 512 hist blocks
constexpr int CAP_  = 16384;           // per-pair sorted capacity (mean 8192, sigma ~450)
constexpr int CAPT_ = 384;             // per-type atom capacity (mean 256, sigma ~14)
constexpr int NROW_ = T_ * CAPT_;      // 1536 sorted-space fitting rows

// ---------------- workspace layout (float offsets) ----------------
constexpr int OFF_X    = 0;                       // x normalized (B,N,SEL,4)     524288
constexpr int OFF_SS   = 524288;                  // s sorted by pair             262144
constexpr int OFF_SI   = OFF_SS + P_ * CAP_;      // src idx sorted (int)         262144
constexpr int OFF_CNTP = OFF_SI + P_ * CAP_;      // pair counts (16 int)
constexpr int OFF_CNTT = OFF_CNTP + 16;           // type counts (4 int)
constexpr int OFF_AIDX = 1048608;                 // atom idx sorted by type (1536 int)
constexpr int OFF_G    = 1052672;                 // G (131072 x 128)             16777216
// ---- overlaid into the G region, phase 1 (dead once k_embed writes G) ----
constexpr int OFF_HIST = OFF_G;                   // hist   512x16 int
constexpr int OFF_BASE = OFF_G + NBLK_ * 16;      // base   512x16 int
constexpr int OFF_RANK = OFF_BASE + NBLK_ * 16;   // rank   131072 u8 (= 32768 floats)
// ---- overlaid into the G region, phase 2 (G dead after k_grd) ----
constexpr int OFF_PART = OFF_G;                   // layer0 K-split partials 8x1536x256
constexpr int OFF_HA   = OFF_G + 8 * NROW_ * H_;  // 1536x256
constexpr int OFF_HB   = OFF_HA + NROW_ * H_;     // 1536x256  (ends well inside G)
// ---- after G region ----
constexpr int OFF_D    = OFF_G + NBT_ * F2_;      // D (1024 x 2048)              2097152
constexpr int WS_FLOATS = OFF_D + NA_ * DIN_;     // 19,927,040 floats = 79.7 MB

__device__ __forceinline__ float tanh_fast(float x) {
  // 1 - 2/(e^{2x}+1): v_exp + v_rcp path, abs err ~1e-7, correct saturation at +-inf
  return 1.0f - 2.0f / (__expf(2.0f * x) + 1.0f);
}
__device__ __forceinline__ float4 tanh4(float4 v) {
  return make_float4(tanh_fast(v.x), tanh_fast(v.y), tanh_fast(v.z), tanh_fast(v.w));
}
__device__ __forceinline__ void fma4(float4& acc, float a, const float4& b) {
  acc.x += a * b.x; acc.y += a * b.y; acc.z += a * b.z; acc.w += a * b.w;
}
__device__ __forceinline__ float4 add4(float4 a, float4 b) {
  return make_float4(a.x + b.x, a.y + b.y, a.z + b.z, a.w + b.w);
}

// canary: ws too small -> report ws_size through d_out instead of faulting
__global__ void k_canary(float* out, float wsz) { out[0] = wsz; out[1] = -12345.0f; }

// ================= K1a: normalize + per-block pair histogram + stable rank =======
__global__ void k_hist(const float* __restrict__ sym, const float* __restrict__ stdv,
                       const float* __restrict__ avgv, const int* __restrict__ atype,
                       const int* __restrict__ ntype, float* __restrict__ x_ws,
                       int* __restrict__ hist, unsigned char* __restrict__ rank) {
  __shared__ int whist[4][16];                    // per-wave per-pair counts
  int tid = threadIdx.x;
  int gid = blockIdx.x * 256 + tid;
  int wave = tid >> 6, lane = tid & 63;
  unsigned long long below = (1ull << lane) - 1ull;
  if (tid < 64) whist[tid >> 4][tid & 15] = 0;
  __syncthreads();

  int at = atype[gid >> 7];                       // wave-uniform (64 | SEL)
  int nt = ntype[gid];
  float4 c = ((const float4*)sym)[gid];
  float x0 = (c.x - avgv[at * 4 + 0]) / stdv[at * 4 + 0];
  float x1 = (c.y - avgv[at * 4 + 1]) / stdv[at * 4 + 1];
  float x2 = (c.z - avgv[at * 4 + 2]) / stdv[at * 4 + 2];
  float x3 = (c.w - avgv[at * 4 + 3]) / stdv[at * 4 + 3];
  ((float4*)x_ws)[gid] = make_float4(x0, x1, x2, x3);

  int myrank = 0;
#pragma unroll
  for (int k = 0; k < 4; k++) {
    unsigned long long mk = __ballot(nt == k);
    if (lane == 0) whist[wave][at * 4 + k] = __popcll(mk);
    if (nt == k) myrank = __popcll(mk & below);
  }
  __syncthreads();
  int pair = at * 4 + nt;
  int r = myrank;
  for (int w = 0; w < wave; w++) r += whist[w][pair];
  rank[gid] = (unsigned char)r;                   // < 256 always
  if (tid < 16)
    hist[blockIdx.x * 16 + tid] =
        whist[0][tid] + whist[1][tid] + whist[2][tid] + whist[3][tid];
}

// ================= K1b: scan (1 block, 1024 thr): pair bases + atom type sort ====
__global__ void k_scan(const int* __restrict__ hist, int* __restrict__ base,
                       int* __restrict__ cnt_pair, const int* __restrict__ atype,
                       int* __restrict__ aidx, int* __restrict__ cnt_type,
                       float* __restrict__ out) {
  __shared__ int awhist[16][4];
  __shared__ int apre[16][4];
  int tid = threadIdx.x;
  int wave = tid >> 6, lane = tid & 63;           // 16 waves
  unsigned long long below = (1ull << lane) - 1ull;

  // part 1: wave p scans pair p across the 512 block histograms
  {
    int p = wave;
    int carry = 0;
    for (int rr = 0; rr < NBLK_ / 64; rr++) {
      int b = rr * 64 + lane;
      int v = hist[b * 16 + p];
      int incl = v;
#pragma unroll
      for (int d = 1; d < 64; d <<= 1) {
        int o = __shfl_up(incl, d, 64);
        if (lane >= d) incl += o;
      }
      base[b * 16 + p] = carry + incl - v;        // exclusive prefix
      carry += __shfl(incl, 63, 64);
    }
    if (lane == 0) cnt_pair[p] = carry;
  }

  // part 2: atom type sort (1024 atoms == 1024 threads)
  int at = atype[tid];
  int arank = 0;
#pragma unroll
  for (int t = 0; t < 4; t++) {
    unsigned long long mk = __ballot(at == t);
    if (lane == 0) awhist[wave][t] = __popcll(mk);
    if (at == t) arank = __popcll(mk & below);
  }
  __syncthreads();
  if (tid < 4) {                                  // thread t: prefix over 16 waves
    int s = 0;
    for (int w = 0; w < 16; w++) { apre[w][tid] = s; s += awhist[w][tid]; }
    cnt_type[tid] = s;
  }
  if (tid < B_) out[tid] = 0.0f;                  // zero d_out here
  __syncthreads();
  int pos = apre[wave][at] + arank;
  if (pos < CAPT_) aidx[at * CAPT_ + pos] = tid;
}

// ================= K1c: scatter into pair-sorted arrays ==========================
__global__ void k_scatter(const float* __restrict__ x_ws, const int* __restrict__ atype,
                          const int* __restrict__ ntype,
                          const unsigned char* __restrict__ rank,
                          const int* __restrict__ base, float* __restrict__ s_sorted,
                          int* __restrict__ idx_sorted) {
  int gid = blockIdx.x * 256 + threadIdx.x;
  int at = atype[gid >> 7];
  int nt = ntype[gid];
  int pair = at * 4 + nt;
  int pos = base[blockIdx.x * 16 + pair] + (int)rank[gid];
  float x0 = x_ws[gid * 4];
  if (pos < CAP_) {                               // defensive (never expected)
    s_sorted[pair * CAP_ + pos] = x0;
    idx_sorted[pair * CAP_ + pos] = gid;
  }
}

// ================= K2: embedding MLP 1->32->64->128 per (pair, 64-row chunk) ======
// Same launch_bounds as the known-good round-7 kernel; only the LDS access pattern
// changed: all LDS matrix I/O is float4 (ds_read_b128/ds_write_b128), k-blocked by 4.
// Row strides 36/68 floats: 16B-aligned, ≡4 mod 32 so different-row lanes spread banks.
__global__ __launch_bounds__(256, 2) void k_embed(
    const float* __restrict__ Wf0, const float* __restrict__ bf0,
    const float* __restrict__ Wf1, const float* __restrict__ bf1,
    const float* __restrict__ Wf2, const float* __restrict__ bf2,
    const float* __restrict__ s_sorted, const int* __restrict__ idx_sorted,
    const int* __restrict__ cnt_pair, float* __restrict__ G) {
  __shared__ float W0s[32], b0s[32], b1s[64], b2s[128];
  __shared__ float W1s[32 * 64];     // [k][c]
  __shared__ float W2s[32 * 128];    // [k][c], one 32-row half at a time
  __shared__ float H0s[64 * 36];
  __shared__ float H1s[64 * 68];
  __shared__ float ss[64];
  __shared__ int   idxs[64];

  int p = blockIdx.y;
  int cnt = cnt_pair[p];
  int r0g = blockIdx.x * 64;
  if (r0g >= cnt) return;
  int m = min(64, cnt - r0g);
  int tid = threadIdx.x;

  for (int i = tid; i < 512; i += 256)
    ((float4*)W1s)[i] = ((const float4*)(Wf1 + p * 2048))[i];
  for (int i = tid; i < 1024; i += 256)                       // W2 rows 0..31
    ((float4*)W2s)[i] = ((const float4*)(Wf2 + p * 8192))[i];
  if (tid < 32) { W0s[tid] = Wf0[p * 32 + tid]; b0s[tid] = bf0[p * 32 + tid]; }
  else if (tid < 96)  b1s[tid - 32] = bf1[p * 64 + tid - 32];
  else if (tid < 224) b2s[tid - 96] = bf2[p * 128 + tid - 96];
  if (tid < 64) {
    ss[tid]   = s_sorted[p * CAP_ + r0g + tid];
    idxs[tid] = idx_sorted[p * CAP_ + r0g + tid];
  }
  __syncthreads();

  // H0: 64x32, 8 outputs/thread, float4 stores
  {
    int row = tid >> 2, j0 = (tid & 3) * 8;
    float s = ss[row];
    float4 oA, oB;
    oA.x = tanh_fast(s * W0s[j0 + 0] + b0s[j0 + 0]);
    oA.y = tanh_fast(s * W0s[j0 + 1] + b0s[j0 + 1]);
    oA.z = tanh_fast(s * W0s[j0 + 2] + b0s[j0 + 2]);
    oA.w = tanh_fast(s * W0s[j0 + 3] + b0s[j0 + 3]);
    oB.x = tanh_fast(s * W0s[j0 + 4] + b0s[j0 + 4]);
    oB.y = tanh_fast(s * W0s[j0 + 5] + b0s[j0 + 5]);
    oB.z = tanh_fast(s * W0s[j0 + 6] + b0s[j0 + 6]);
    oB.w = tanh_fast(s * W0s[j0 + 7] + b0s[j0 + 7]);
    *(float4*)&H0s[row * 36 + j0]     = oA;
    *(float4*)&H0s[row * 36 + j0 + 4] = oB;
  }
  __syncthreads();

  int rowtile = tid >> 4, coltile = tid & 15;
  int r0 = rowtile * 4;

  // H1 = tanh(H0 @ W1 + b1): 64x64, 4x4 tiles, k-blocked float4 reads
  {
    int c0 = coltile * 4;
    float4 acc[4] = {};
#pragma unroll
    for (int kb = 0; kb < 32; kb += 4) {
      const float4 A0 = *(const float4*)&H0s[(r0 + 0) * 36 + kb];
      const float4 A1 = *(const float4*)&H0s[(r0 + 1) * 36 + kb];
      const float4 A2 = *(const float4*)&H0s[(r0 + 2) * 36 + kb];
      const float4 A3 = *(const float4*)&H0s[(r0 + 3) * 36 + kb];
#pragma unroll
      for (int j = 0; j < 4; j++) {
        const float4 Bj = *(const float4*)&W1s[(kb + j) * 64 + c0];
        const float a0 = j == 0 ? A0.x : j == 1 ? A0.y : j == 2 ? A0.z : A0.w;
        const float a1 = j == 0 ? A1.x : j == 1 ? A1.y : j == 2 ? A1.z : A1.w;
        const float a2 = j == 0 ? A2.x : j == 1 ? A2.y : j == 2 ? A2.z : A2.w;
        const float a3 = j == 0 ? A3.x : j == 1 ? A3.y : j == 2 ? A3.z : A3.w;
        fma4(acc[0], a0, Bj); fma4(acc[1], a1, Bj);
        fma4(acc[2], a2, Bj); fma4(acc[3], a3, Bj);
      }
    }
    const float4 bb = *(const float4*)&b1s[c0];
#pragma unroll
    for (int i = 0; i < 4; i++)
      *(float4*)&H1s[(r0 + i) * 68 + c0] = tanh4(add4(acc[i], bb));
  }
  __syncthreads();

  // G = tanh(H1 @ W2 + b2): 64x128, 4x8 tiles; W2 staged 32 k-rows per half
  {
    int c0g = coltile * 8;
    float4 accA[4] = {};
    float4 accB[4] = {};
#pragma unroll
    for (int half = 0; half < 2; half++) {
      if (half == 1) {
        __syncthreads();                                      // all done with half 0
        for (int i = tid; i < 1024; i += 256)                 // W2 rows 32..63
          ((float4*)W2s)[i] = ((const float4*)(Wf2 + p * 8192 + 4096))[i];
        __syncthreads();
      }
      const int koff = half * 32;
#pragma unroll
      for (int kb = 0; kb < 32; kb += 4) {
        const float4 A0 = *(const float4*)&H1s[(r0 + 0) * 68 + koff + kb];
        const float4 A1 = *(const float4*)&H1s[(r0 + 1) * 68 + koff + kb];
        const float4 A2 = *(const float4*)&H1s[(r0 + 2) * 68 + koff + kb];
        const float4 A3 = *(const float4*)&H1s[(r0 + 3) * 68 + koff + kb];
#pragma unroll
        for (int j = 0; j < 4; j++) {
          const float4 BA = *(const float4*)&W2s[(kb + j) * 128 + c0g];
          const float4 BB = *(const float4*)&W2s[(kb + j) * 128 + c0g + 4];
          const float a0 = j == 0 ? A0.x : j == 1 ? A0.y : j == 2 ? A0.z : A0.w;
          const float a1 = j == 0 ? A1.x : j == 1 ? A1.y : j == 2 ? A1.z : A1.w;
          const float a2 = j == 0 ? A2.x : j == 1 ? A2.y : j == 2 ? A2.z : A2.w;
          const float a3 = j == 0 ? A3.x : j == 1 ? A3.y : j == 2 ? A3.z : A3.w;
          fma4(accA[0], a0, BA); fma4(accB[0], a0, BB);
          fma4(accA[1], a1, BA); fma4(accB[1], a1, BB);
          fma4(accA[2], a2, BA); fma4(accB[2], a2, BB);
          fma4(accA[3], a3, BA); fma4(accB[3], a3, BB);
        }
      }
    }
    const float4 bbA = *(const float4*)&b2s[c0g];
    const float4 bbB = *(const float4*)&b2s[c0g + 4];
#pragma unroll
    for (int i = 0; i < 4; i++) {
      int r = r0 + i;
      if (r < m) {
        int grow = idxs[r] * 128;
        *(float4*)&G[grow + c0g]     = tanh4(add4(accA[i], bbA));
        *(float4*)&G[grow + c0g + 4] = tanh4(add4(accB[i], bbB));
      }
    }
  }
}

// ================= K3: per-atom GR = G^T x / S, D = GR @ GR[:16]^T ================
// Two 64-neighbor passes; GR accumulated in registers. (no launch_bounds, as round 7)
__global__ void k_grd(const float* __restrict__ G, const float* __restrict__ x_ws,
                      float* __restrict__ D) {
  __shared__ float Gs[64 * 132];
  __shared__ float xs[64 * 4];
  __shared__ float GRs[512];
  int atom = blockIdx.x;
  int tid = threadIdx.x;
  int m0 = tid >> 2,         d0v = tid & 3;
  int m1 = 64 + (tid >> 2),  d1v = d0v;
  float acc0 = 0.f, acc1 = 0.f;
#pragma unroll
  for (int pass = 0; pass < 2; pass++) {
    for (int i = tid; i < 2048; i += 256) {
      int row = i >> 5, q = i & 31;
      float4 v = ((const float4*)G)[atom * 4096 + pass * 2048 + i];
      *(float4*)&Gs[row * 132 + q * 4] = v;
    }
    if (tid < 64) *(float4*)&xs[tid * 4] = ((const float4*)x_ws)[atom * 128 + pass * 64 + tid];
    __syncthreads();
#pragma unroll 8
    for (int s = 0; s < 64; s++) {
      acc0 += Gs[s * 132 + m0] * xs[s * 4 + d0v];
      acc1 += Gs[s * 132 + m1] * xs[s * 4 + d1v];
    }
    __syncthreads();
  }
  GRs[tid]       = acc0 * (1.0f / 128.0f);
  GRs[tid + 256] = acc1 * (1.0f / 128.0f);
  __syncthreads();
  int o0 = tid * 8;
  float out[8];
#pragma unroll
  for (int j = 0; j < 8; j++) {
    int o = o0 + j;
    int mm = o >> 4, kk = o & 15;
    out[j] = GRs[mm * 4 + 0] * GRs[kk * 4 + 0] + GRs[mm * 4 + 1] * GRs[kk * 4 + 1] +
             GRs[mm * 4 + 2] * GRs[kk * 4 + 2] + GRs[mm * 4 + 3] * GRs[kk * 4 + 3];
  }
  *(float4*)&D[atom * 2048 + o0]     = make_float4(out[0], out[1], out[2], out[3]);
  *(float4*)&D[atom * 2048 + o0 + 4] = make_float4(out[4], out[5], out[6], out[7]);
}

// ================= fitting GEMM: 64 rows x 64 cols, Kt=64 stages =================
// GATHER: rows gathered from D via aidx (layer0); else contiguous sorted Hbuf rows.
// KSPLIT: layer0 8-way K split -> write raw partials (bias/tanh in reduce kernel).
// launch_bounds as round 7; float4 LDS I/O throughout, k-blocked by 4.
template <bool GATHER, bool KSPLIT>
__global__ __launch_bounds__(256, 2) void k_fit(const float* __restrict__ Ain,
                                                const float* __restrict__ W,
                                                const float* __restrict__ bias,
                                                const int* __restrict__ cnt_type,
                                                const int* __restrict__ aidx,
                                                float* __restrict__ Out) {
  __shared__ float As[64 * 68];
  __shared__ float Ws[64 * 68];
  __shared__ int gidx[64];
  constexpr int KTOT = GATHER ? 2048 : 256;
  int rc = blockIdx.x, cc = blockIdx.y, z = blockIdx.z;
  int t  = KSPLIT ? (z >> 3) : z;
  int ks = KSPLIT ? (z & 7) : 0;
  int cnt = cnt_type[t];
  int r0g = rc * 64;
  if (r0g >= cnt) return;
  int m = min(64, cnt - r0g);
  int tid = threadIdx.x;
  int c0g = cc * 64;
  int k0base = ks * 256;

  if (GATHER && tid < 64)
    gidx[tid] = (r0g + tid < cnt) ? aidx[t * CAPT_ + r0g + tid] : aidx[t * CAPT_];
  __syncthreads();

  float4 acc[4] = {};
  int arow = tid >> 2, ak0 = (tid & 3) * 16;
  int rowtile = tid >> 4, coltile = tid & 15;
  int r0 = rowtile * 4, c0 = coltile * 4;

  for (int kt = 0; kt < 4; kt++) {
    int k0 = k0base + kt * 64;
    const float* ap;
    if (GATHER) ap = Ain + gidx[arow] * DIN_ + k0 + ak0;
    else        ap = Ain + (t * CAPT_ + r0g + arow) * 256 + k0 + ak0;
#pragma unroll
    for (int i = 0; i < 4; i++)
      *(float4*)&As[arow * 68 + ak0 + 4 * i] = ((const float4*)ap)[i];
    int wk = tid >> 2, wc0 = (tid & 3) * 16;
    const float* wp = W + (t * KTOT + k0 + wk) * 256 + c0g + wc0;
#pragma unroll
    for (int i = 0; i < 4; i++)
      *(float4*)&Ws[wk * 68 + wc0 + 4 * i] = ((const float4*)wp)[i];
    __syncthreads();
#pragma unroll
    for (int kb = 0; kb < 64; kb += 4) {
      const float4 A0 = *(const float4*)&As[(r0 + 0) * 68 + kb];
      const float4 A1 = *(const float4*)&As[(r0 + 1) * 68 + kb];
      const float4 A2 = *(const float4*)&As[(r0 + 2) * 68 + kb];
      const float4 A3 = *(const float4*)&As[(r0 + 3) * 68 + kb];
#pragma unroll
      for (int j = 0; j < 4; j++) {
        const float4 Bj = *(const float4*)&Ws[(kb + j) * 68 + c0];
        const float a0 = j == 0 ? A0.x : j == 1 ? A0.y : j == 2 ? A0.z : A0.w;
        const float a1 = j == 0 ? A1.x : j == 1 ? A1.y : j == 2 ? A1.z : A1.w;
        const float a2 = j == 0 ? A2.x : j == 1 ? A2.y : j == 2 ? A2.z : A2.w;
        const float a3 = j == 0 ? A3.x : j == 1 ? A3.y : j == 2 ? A3.z : A3.w;
        fma4(acc[0], a0, Bj); fma4(acc[1], a1, Bj);
        fma4(acc[2], a2, Bj); fma4(acc[3], a3, Bj);
      }
    }
    __syncthreads();
  }
#pragma unroll
  for (int i = 0; i < 4; i++) {
    int r = r0 + i;
    if (r < m) {
      int row = t * CAPT_ + r0g + r;
      if (KSPLIT) {
        *(float4*)&Out[(ks * NROW_ + row) * 256 + c0g + c0] = acc[i];
      } else {
        const float4 bb = *(const float4*)&bias[t * 256 + c0g + c0];
        *(float4*)&Out[row * 256 + c0g + c0] = tanh4(add4(acc[i], bb));
      }
    }
  }
}

// ================= layer0 K-split reduce + bias + tanh ===========================
__global__ void k_fit0_reduce(const float* __restrict__ Part,
                              const float* __restrict__ bg0, float* __restrict__ HA) {
  int idx = blockIdx.x * 256 + threadIdx.x;   // over NROW_*256
  int row = idx >> 8;
  int t = row / CAPT_;
  int c = idx & 255;
  float s = 0.f;
#pragma unroll
  for (int ks = 0; ks < 8; ks++) s += Part[ks * (NROW_ * 256) + idx];
  HA[idx] = tanh_fast(s + bg0[t * 256 + c]);
}

// ================= output layer + per-batch energy sum ===========================
__global__ void k_out(const float* __restrict__ HA, const float* __restrict__ Wgo,
                      const float* __restrict__ bgo, const int* __restrict__ cnt_type,
                      const int* __restrict__ aidx, float* __restrict__ out) {
  __shared__ float red[64][4];
  __shared__ float eb[B_];
  int rc = blockIdx.x, t = blockIdx.y;
  int cnt = cnt_type[t];
  int r0g = rc * 64;
  int tid = threadIdx.x;
  if (tid < B_) eb[tid] = 0.f;
  __syncthreads();
  int m = cnt - r0g;
  int r = tid >> 2, part = tid & 3;
  float acc = 0.f;
  if (m > 0 && r < m) {
    const float* hp = HA + (t * CAPT_ + r0g + r) * 256 + part * 64;
    const float* wp = Wgo + t * 256 + part * 64;
#pragma unroll 8
    for (int c = 0; c < 64; c++) acc += hp[c] * wp[c];
  }
  red[r][part] = acc;
  __syncthreads();
  if (part == 0 && m > 0 && r < m) {
    float e = red[r][0] + red[r][1] + red[r][2] + red[r][3] + bgo[t];
    int flat = aidx[t * CAPT_ + r0g + r];
    atomicAdd(&eb[flat >> 9], e);            // b = flat / N_
  }
  __syncthreads();
  if (tid < B_) atomicAdd(&out[tid], eb[tid]);
}

// =================================================================================
extern "C" void kernel_launch(void* const* d_in, const int* in_sizes, int n_in,
                              void* d_out, int out_size, void* d_ws, size_t ws_size,
                              hipStream_t stream) {
  // ws canary: if the workspace is too small, report its size instead of faulting
  if (ws_size < (size_t)WS_FLOATS * sizeof(float)) {
    k_canary<<<1, 1, 0, stream>>>((float*)d_out, (float)ws_size);
    return;
  }

  const float* sym  = (const float*)d_in[0];
  const float* stdv = (const float*)d_in[1];
  const float* avgv = (const float*)d_in[2];
  const int* atype  = (const int*)d_in[3];
  const int* ntype  = (const int*)d_in[4];
  const float* Wf0 = (const float*)d_in[5];
  const float* bf0 = (const float*)d_in[6];
  const float* Wf1 = (const float*)d_in[7];
  const float* bf1 = (const float*)d_in[8];
  const float* Wf2 = (const float*)d_in[9];
  const float* bf2 = (const float*)d_in[10];
  const float* Wg0 = (const float*)d_in[11];
  const float* bg0 = (const float*)d_in[12];
  const float* Wg1 = (const float*)d_in[13];
  const float* bg1 = (const float*)d_in[14];
  const float* Wg2 = (const float*)d_in[15];
  const float* bg2 = (const float*)d_in[16];
  const float* Wgo = (const float*)d_in[17];
  const float* bgo = (const float*)d_in[18];

  float* ws = (float*)d_ws;
  float* x_ws      = ws + OFF_X;
  float* s_sorted  = ws + OFF_SS;
  int*   idx_sorted= (int*)(ws + OFF_SI);
  int*   cnt_pair  = (int*)(ws + OFF_CNTP);
  int*   cnt_type  = (int*)(ws + OFF_CNTT);
  int*   aidx      = (int*)(ws + OFF_AIDX);
  int*   hist      = (int*)(ws + OFF_HIST);
  int*   base      = (int*)(ws + OFF_BASE);
  unsigned char* rank = (unsigned char*)(ws + OFF_RANK);
  float* G_ws      = ws + OFF_G;
  float* D_ws      = ws + OFF_D;
  float* Part      = ws + OFF_PART;
  float* HA        = ws + OFF_HA;
  float* HB        = ws + OFF_HB;

  k_hist<<<NBLK_, 256, 0, stream>>>(sym, stdv, avgv, atype, ntype, x_ws, hist, rank);
  k_scan<<<1, 1024, 0, stream>>>(hist, base, cnt_pair, atype, aidx, cnt_type,
                                 (float*)d_out);
  k_scatter<<<NBLK_, 256, 0, stream>>>(x_ws, atype, ntype, rank, base,
                                       s_sorted, idx_sorted);
  k_embed<<<dim3(160, 16), 256, 0, stream>>>(Wf0, bf0, Wf1, bf1, Wf2, bf2,
                                             s_sorted, idx_sorted, cnt_pair, G_ws);
  k_grd<<<NA_, 256, 0, stream>>>(G_ws, x_ws, D_ws);
  k_fit<true, true><<<dim3(6, 4, 32), 256, 0, stream>>>(D_ws, Wg0, bg0, cnt_type, aidx, Part);
  k_fit0_reduce<<<NROW_, 256, 0, stream>>>(Part, bg0, HA);
  k_fit<false, false><<<dim3(6, 4, 4), 256, 0, stream>>>(HA, Wg1, bg1, cnt_type, aidx, HB);
  k_fit<false, false><<<dim3(6, 4, 4), 256, 0, stream>>>(HB, Wg2, bg2, cnt_type, aidx, HA);
  k_out<<<dim3(6, 4), 256, 0, stream>>>(HA, Wgo, bgo, cnt_type, aidx, (float*)d_out);
}

// Round 11
// 258.371 us; speedup vs baseline: 5.2998x; 5.2998x over previous
//
#include <hip/hip_runtime.h>

// ---------------- problem constants ----------------
constexpr int B_ = 2, N_ = 512, SEL_ = 128, T_ = 4, P_ = 16;
constexpr int F2_ = 128, H_ = 256, DIN_ = 2048;
constexpr int NBT_ = B_ * N_ * SEL_;   // 131072 neighbors
constexpr int NA_  = B_ * N_;          // 1024 atoms
constexpr int NBLK_ = NBT_ / 256;      // 512 hist blocks
constexpr int CAP_  = 16384;           // per-pair sorted capacity (mean 8192, sigma ~450)
constexpr int CAPT_ = 384;             // per-type atom capacity (mean 256, sigma ~14)
constexpr int NROW_ = T_ * CAPT_;      // 1536 sorted-space fitting rows

// ---------------- workspace layout (float offsets) ----------------
constexpr int OFF_X    = 0;                       // x normalized (B,N,SEL,4)     524288
constexpr int OFF_SS   = 524288;                  // s sorted by pair             262144
constexpr int OFF_SI   = OFF_SS + P_ * CAP_;      // src idx sorted (int)         262144
constexpr int OFF_CNTP = OFF_SI + P_ * CAP_;      // pair counts (16 int)
constexpr int OFF_CNTT = OFF_CNTP + 16;           // type counts (4 int)
constexpr int OFF_AIDX = 1048608;                 // atom idx sorted by type (1536 int)
constexpr int OFF_G    = 1052672;                 // G (131072 x 128)             16777216
// ---- overlaid into the G region, phase 1 (dead once k_embed writes G) ----
constexpr int OFF_HIST = OFF_G;                   // hist   512x16 int
constexpr int OFF_BASE = OFF_G + NBLK_ * 16;      // base   512x16 int
constexpr int OFF_RANK = OFF_BASE + NBLK_ * 16;   // rank   131072 u8 (= 32768 floats)
// ---- overlaid into the G region, phase 2 (G dead after k_grd) ----
constexpr int OFF_PART = OFF_G;                   // layer0 K-split partials 8x1536x256
constexpr int OFF_HA   = OFF_G + 8 * NROW_ * H_;  // 1536x256
constexpr int OFF_HB   = OFF_HA + NROW_ * H_;     // 1536x256  (ends well inside G)
// ---- after G region ----
constexpr int OFF_D    = OFF_G + NBT_ * F2_;      // D (1024 x 2048)              2097152
constexpr int WS_FLOATS = OFF_D + NA_ * DIN_;     // 19,927,040 floats = 79.7 MB

__device__ __forceinline__ float tanh_fast(float x) {
  // 1 - 2/(e^{2x}+1): v_exp + v_rcp path, abs err ~1e-7, correct saturation at +-inf
  return 1.0f - 2.0f / (__expf(2.0f * x) + 1.0f);
}
__device__ __forceinline__ float4 tanh4(float4 v) {
  return make_float4(tanh_fast(v.x), tanh_fast(v.y), tanh_fast(v.z), tanh_fast(v.w));
}
__device__ __forceinline__ void fma4(float4& acc, float a, const float4& b) {
  acc.x += a * b.x; acc.y += a * b.y; acc.z += a * b.z; acc.w += a * b.w;
}
__device__ __forceinline__ float4 add4(float4 a, float4 b) {
  return make_float4(a.x + b.x, a.y + b.y, a.z + b.z, a.w + b.w);
}

// canary: ws too small -> report ws_size through d_out instead of faulting
__global__ void k_canary(float* out, float wsz) { out[0] = wsz; out[1] = -12345.0f; }

// ================= K1a: normalize + per-block pair histogram + stable rank =======
__global__ void k_hist(const float* __restrict__ sym, const float* __restrict__ stdv,
                       const float* __restrict__ avgv, const int* __restrict__ atype,
                       const int* __restrict__ ntype, float* __restrict__ x_ws,
                       int* __restrict__ hist, unsigned char* __restrict__ rank) {
  __shared__ int whist[4][16];                    // per-wave per-pair counts
  int tid = threadIdx.x;
  int gid = blockIdx.x * 256 + tid;
  int wave = tid >> 6, lane = tid & 63;
  unsigned long long below = (1ull << lane) - 1ull;
  if (tid < 64) whist[tid >> 4][tid & 15] = 0;
  __syncthreads();

  int at = atype[gid >> 7];                       // wave-uniform (64 | SEL)
  int nt = ntype[gid];
  float4 c = ((const float4*)sym)[gid];
  float x0 = (c.x - avgv[at * 4 + 0]) / stdv[at * 4 + 0];
  float x1 = (c.y - avgv[at * 4 + 1]) / stdv[at * 4 + 1];
  float x2 = (c.z - avgv[at * 4 + 2]) / stdv[at * 4 + 2];
  float x3 = (c.w - avgv[at * 4 + 3]) / stdv[at * 4 + 3];
  ((float4*)x_ws)[gid] = make_float4(x0, x1, x2, x3);

  int myrank = 0;
#pragma unroll
  for (int k = 0; k < 4; k++) {
    unsigned long long mk = __ballot(nt == k);
    if (lane == 0) whist[wave][at * 4 + k] = __popcll(mk);
    if (nt == k) myrank = __popcll(mk & below);
  }
  __syncthreads();
  int pair = at * 4 + nt;
  int r = myrank;
  for (int w = 0; w < wave; w++) r += whist[w][pair];
  rank[gid] = (unsigned char)r;                   // < 256 always
  if (tid < 16)
    hist[blockIdx.x * 16 + tid] =
        whist[0][tid] + whist[1][tid] + whist[2][tid] + whist[3][tid];
}

// ================= K1b: scan (1 block, 1024 thr): pair bases + atom type sort ====
__global__ void k_scan(const int* __restrict__ hist, int* __restrict__ base,
                       int* __restrict__ cnt_pair, const int* __restrict__ atype,
                       int* __restrict__ aidx, int* __restrict__ cnt_type,
                       float* __restrict__ out) {
  __shared__ int awhist[16][4];
  __shared__ int apre[16][4];
  int tid = threadIdx.x;
  int wave = tid >> 6, lane = tid & 63;           // 16 waves
  unsigned long long below = (1ull << lane) - 1ull;

  // part 1: wave p scans pair p across the 512 block histograms
  {
    int p = wave;
    int carry = 0;
    for (int rr = 0; rr < NBLK_ / 64; rr++) {
      int b = rr * 64 + lane;
      int v = hist[b * 16 + p];
      int incl = v;
#pragma unroll
      for (int d = 1; d < 64; d <<= 1) {
        int o = __shfl_up(incl, d, 64);
        if (lane >= d) incl += o;
      }
      base[b * 16 + p] = carry + incl - v;        // exclusive prefix
      carry += __shfl(incl, 63, 64);
    }
    if (lane == 0) cnt_pair[p] = carry;
  }

  // part 2: atom type sort (1024 atoms == 1024 threads)
  int at = atype[tid];
  int arank = 0;
#pragma unroll
  for (int t = 0; t < 4; t++) {
    unsigned long long mk = __ballot(at == t);
    if (lane == 0) awhist[wave][t] = __popcll(mk);
    if (at == t) arank = __popcll(mk & below);
  }
  __syncthreads();
  if (tid < 4) {                                  // thread t: prefix over 16 waves
    int s = 0;
    for (int w = 0; w < 16; w++) { apre[w][tid] = s; s += awhist[w][tid]; }
    cnt_type[tid] = s;
  }
  if (tid < B_) out[tid] = 0.0f;                  // zero d_out here
  __syncthreads();
  int pos = apre[wave][at] + arank;
  if (pos < CAPT_) aidx[at * CAPT_ + pos] = tid;
}

// ================= K1c: scatter into pair-sorted arrays ==========================
__global__ void k_scatter(const float* __restrict__ x_ws, const int* __restrict__ atype,
                          const int* __restrict__ ntype,
                          const unsigned char* __restrict__ rank,
                          const int* __restrict__ base, float* __restrict__ s_sorted,
                          int* __restrict__ idx_sorted) {
  int gid = blockIdx.x * 256 + threadIdx.x;
  int at = atype[gid >> 7];
  int nt = ntype[gid];
  int pair = at * 4 + nt;
  int pos = base[blockIdx.x * 16 + pair] + (int)rank[gid];
  float x0 = x_ws[gid * 4];
  if (pos < CAP_) {                               // defensive (never expected)
    s_sorted[pair * CAP_ + pos] = x0;
    idx_sorted[pair * CAP_ + pos] = gid;
  }
}

// ================= K2: embedding MLP 1->32->64->128 per (pair, 64-row chunk) ======
// Float4 k-blocked LDS reads (4x fewer LDS issue slots than round-7 scalar), with
// ALL accumulators/operands as NAMED float4s (no arrays) to prevent scratch spill
// (round-10 lesson: float4 acc[4] arrays -> 2GB scratch traffic, 18x slowdown).
// Row strides 36/68 floats: 16B-aligned; pads keep different-row lanes off one bank.
__global__ __launch_bounds__(256, 2) void k_embed(
    const float* __restrict__ Wf0, const float* __restrict__ bf0,
    const float* __restrict__ Wf1, const float* __restrict__ bf1,
    const float* __restrict__ Wf2, const float* __restrict__ bf2,
    const float* __restrict__ s_sorted, const int* __restrict__ idx_sorted,
    const int* __restrict__ cnt_pair, float* __restrict__ G) {
  __shared__ float W0s[32], b0s[32], b1s[64], b2s[128];
  __shared__ float W1s[32 * 64];     // [k][c]
  __shared__ float W2s[32 * 128];    // [k][c], one 32-row half at a time
  __shared__ float H0s[64 * 36];
  __shared__ float H1s[64 * 68];
  __shared__ float ss[64];
  __shared__ int   idxs[64];

  int p = blockIdx.y;
  int cnt = cnt_pair[p];
  int r0g = blockIdx.x * 64;
  if (r0g >= cnt) return;
  int m = min(64, cnt - r0g);
  int tid = threadIdx.x;

  for (int i = tid; i < 512; i += 256)
    ((float4*)W1s)[i] = ((const float4*)(Wf1 + p * 2048))[i];
  for (int i = tid; i < 1024; i += 256)                       // W2 rows 0..31
    ((float4*)W2s)[i] = ((const float4*)(Wf2 + p * 8192))[i];
  if (tid < 32) { W0s[tid] = Wf0[p * 32 + tid]; b0s[tid] = bf0[p * 32 + tid]; }
  else if (tid < 96)  b1s[tid - 32] = bf1[p * 64 + tid - 32];
  else if (tid < 224) b2s[tid - 96] = bf2[p * 128 + tid - 96];
  if (tid < 64) {
    ss[tid]   = s_sorted[p * CAP_ + r0g + tid];
    idxs[tid] = idx_sorted[p * CAP_ + r0g + tid];
  }
  __syncthreads();

  // H0: 64x32, 8 outputs/thread, float4 stores (named)
  {
    int row = tid >> 2, j0 = (tid & 3) * 8;
    float s = ss[row];
    float4 oA, oB;
    oA.x = tanh_fast(s * W0s[j0 + 0] + b0s[j0 + 0]);
    oA.y = tanh_fast(s * W0s[j0 + 1] + b0s[j0 + 1]);
    oA.z = tanh_fast(s * W0s[j0 + 2] + b0s[j0 + 2]);
    oA.w = tanh_fast(s * W0s[j0 + 3] + b0s[j0 + 3]);
    oB.x = tanh_fast(s * W0s[j0 + 4] + b0s[j0 + 4]);
    oB.y = tanh_fast(s * W0s[j0 + 5] + b0s[j0 + 5]);
    oB.z = tanh_fast(s * W0s[j0 + 6] + b0s[j0 + 6]);
    oB.w = tanh_fast(s * W0s[j0 + 7] + b0s[j0 + 7]);
    *(float4*)&H0s[row * 36 + j0]     = oA;
    *(float4*)&H0s[row * 36 + j0 + 4] = oB;
  }
  __syncthreads();

  int rowtile = tid >> 4, coltile = tid & 15;
  int r0 = rowtile * 4;

  // H1 = tanh(H0 @ W1 + b1): 64x64, 4x4 tiles, k-blocked float4 reads, named accs
  {
    int c0 = coltile * 4;
    float4 accR0 = make_float4(0.f, 0.f, 0.f, 0.f);
    float4 accR1 = accR0, accR2 = accR0, accR3 = accR0;
#pragma unroll
    for (int kb = 0; kb < 32; kb += 4) {
      const float4 a0 = *(const float4*)&H0s[(r0 + 0) * 36 + kb];
      const float4 a1 = *(const float4*)&H0s[(r0 + 1) * 36 + kb];
      const float4 a2 = *(const float4*)&H0s[(r0 + 2) * 36 + kb];
      const float4 a3 = *(const float4*)&H0s[(r0 + 3) * 36 + kb];
      const float4 w0 = *(const float4*)&W1s[(kb + 0) * 64 + c0];
      const float4 w1 = *(const float4*)&W1s[(kb + 1) * 64 + c0];
      const float4 w2 = *(const float4*)&W1s[(kb + 2) * 64 + c0];
      const float4 w3 = *(const float4*)&W1s[(kb + 3) * 64 + c0];
      fma4(accR0, a0.x, w0); fma4(accR0, a0.y, w1); fma4(accR0, a0.z, w2); fma4(accR0, a0.w, w3);
      fma4(accR1, a1.x, w0); fma4(accR1, a1.y, w1); fma4(accR1, a1.z, w2); fma4(accR1, a1.w, w3);
      fma4(accR2, a2.x, w0); fma4(accR2, a2.y, w1); fma4(accR2, a2.z, w2); fma4(accR2, a2.w, w3);
      fma4(accR3, a3.x, w0); fma4(accR3, a3.y, w1); fma4(accR3, a3.z, w2); fma4(accR3, a3.w, w3);
    }
    const float4 bb = *(const float4*)&b1s[c0];
    *(float4*)&H1s[(r0 + 0) * 68 + c0] = tanh4(add4(accR0, bb));
    *(float4*)&H1s[(r0 + 1) * 68 + c0] = tanh4(add4(accR1, bb));
    *(float4*)&H1s[(r0 + 2) * 68 + c0] = tanh4(add4(accR2, bb));
    *(float4*)&H1s[(r0 + 3) * 68 + c0] = tanh4(add4(accR3, bb));
  }
  __syncthreads();

  // G = tanh(H1 @ W2 + b2): 64x128, 4x8 tiles; W2 staged 32 k-rows per half.
  // 8 named float4 accumulators (gA* = cols c0g..c0g+3, gB* = c0g+4..c0g+7).
  {
    int c0g = coltile * 8;
    float4 gA0 = make_float4(0.f, 0.f, 0.f, 0.f);
    float4 gA1 = gA0, gA2 = gA0, gA3 = gA0;
    float4 gB0 = gA0, gB1 = gA0, gB2 = gA0, gB3 = gA0;
    for (int half = 0; half < 2; half++) {
      if (half == 1) {
        __syncthreads();                                      // all done with half 0
        for (int i = tid; i < 1024; i += 256)                 // W2 rows 32..63
          ((float4*)W2s)[i] = ((const float4*)(Wf2 + p * 8192 + 4096))[i];
        __syncthreads();
      }
      const int koff = half * 32;
#pragma unroll
      for (int kb = 0; kb < 32; kb += 4) {
        const float4 a0 = *(const float4*)&H1s[(r0 + 0) * 68 + koff + kb];
        const float4 a1 = *(const float4*)&H1s[(r0 + 1) * 68 + koff + kb];
        const float4 a2 = *(const float4*)&H1s[(r0 + 2) * 68 + koff + kb];
        const float4 a3 = *(const float4*)&H1s[(r0 + 3) * 68 + koff + kb];
        const float4 wA0 = *(const float4*)&W2s[(kb + 0) * 128 + c0g];
        const float4 wB0 = *(const float4*)&W2s[(kb + 0) * 128 + c0g + 4];
        const float4 wA1 = *(const float4*)&W2s[(kb + 1) * 128 + c0g];
        const float4 wB1 = *(const float4*)&W2s[(kb + 1) * 128 + c0g + 4];
        const float4 wA2 = *(const float4*)&W2s[(kb + 2) * 128 + c0g];
        const float4 wB2 = *(const float4*)&W2s[(kb + 2) * 128 + c0g + 4];
        const float4 wA3 = *(const float4*)&W2s[(kb + 3) * 128 + c0g];
        const float4 wB3 = *(const float4*)&W2s[(kb + 3) * 128 + c0g + 4];
        fma4(gA0, a0.x, wA0); fma4(gA0, a0.y, wA1); fma4(gA0, a0.z, wA2); fma4(gA0, a0.w, wA3);
        fma4(gB0, a0.x, wB0); fma4(gB0, a0.y, wB1); fma4(gB0, a0.z, wB2); fma4(gB0, a0.w, wB3);
        fma4(gA1, a1.x, wA0); fma4(gA1, a1.y, wA1); fma4(gA1, a1.z, wA2); fma4(gA1, a1.w, wA3);
        fma4(gB1, a1.x, wB0); fma4(gB1, a1.y, wB1); fma4(gB1, a1.z, wB2); fma4(gB1, a1.w, wB3);
        fma4(gA2, a2.x, wA0); fma4(gA2, a2.y, wA1); fma4(gA2, a2.z, wA2); fma4(gA2, a2.w, wA3);
        fma4(gB2, a2.x, wB0); fma4(gB2, a2.y, wB1); fma4(gB2, a2.z, wB2); fma4(gB2, a2.w, wB3);
        fma4(gA3, a3.x, wA0); fma4(gA3, a3.y, wA1); fma4(gA3, a3.z, wA2); fma4(gA3, a3.w, wA3);
        fma4(gB3, a3.x, wB0); fma4(gB3, a3.y, wB1); fma4(gB3, a3.z, wB2); fma4(gB3, a3.w, wB3);
      }
    }
    const float4 bbA = *(const float4*)&b2s[c0g];
    const float4 bbB = *(const float4*)&b2s[c0g + 4];
    if (r0 + 0 < m) {
      int grow = idxs[r0 + 0] * 128;
      *(float4*)&G[grow + c0g]     = tanh4(add4(gA0, bbA));
      *(float4*)&G[grow + c0g + 4] = tanh4(add4(gB0, bbB));
    }
    if (r0 + 1 < m) {
      int grow = idxs[r0 + 1] * 128;
      *(float4*)&G[grow + c0g]     = tanh4(add4(gA1, bbA));
      *(float4*)&G[grow + c0g + 4] = tanh4(add4(gB1, bbB));
    }
    if (r0 + 2 < m) {
      int grow = idxs[r0 + 2] * 128;
      *(float4*)&G[grow + c0g]     = tanh4(add4(gA2, bbA));
      *(float4*)&G[grow + c0g + 4] = tanh4(add4(gB2, bbB));
    }
    if (r0 + 3 < m) {
      int grow = idxs[r0 + 3] * 128;
      *(float4*)&G[grow + c0g]     = tanh4(add4(gA3, bbA));
      *(float4*)&G[grow + c0g + 4] = tanh4(add4(gB3, bbB));
    }
  }
}

// ================= K3: per-atom GR = G^T x / S, D = GR @ GR[:16]^T ================
// Two 64-neighbor passes; GR accumulated in registers. (round-7 exact)
__global__ void k_grd(const float* __restrict__ G, const float* __restrict__ x_ws,
                      float* __restrict__ D) {
  __shared__ float Gs[64 * 132];
  __shared__ float xs[64 * 4];
  __shared__ float GRs[512];
  int atom = blockIdx.x;
  int tid = threadIdx.x;
  int m0 = tid >> 2,         d0v = tid & 3;
  int m1 = 64 + (tid >> 2),  d1v = d0v;
  float acc0 = 0.f, acc1 = 0.f;
#pragma unroll
  for (int pass = 0; pass < 2; pass++) {
    for (int i = tid; i < 2048; i += 256) {
      int row = i >> 5, q = i & 31;
      float4 v = ((const float4*)G)[atom * 4096 + pass * 2048 + i];
      *(float4*)&Gs[row * 132 + q * 4] = v;
    }
    if (tid < 64) *(float4*)&xs[tid * 4] = ((const float4*)x_ws)[atom * 128 + pass * 64 + tid];
    __syncthreads();
#pragma unroll 8
    for (int s = 0; s < 64; s++) {
      acc0 += Gs[s * 132 + m0] * xs[s * 4 + d0v];
      acc1 += Gs[s * 132 + m1] * xs[s * 4 + d1v];
    }
    __syncthreads();
  }
  GRs[tid]       = acc0 * (1.0f / 128.0f);
  GRs[tid + 256] = acc1 * (1.0f / 128.0f);
  __syncthreads();
  int o0 = tid * 8;
  float out[8];
#pragma unroll
  for (int j = 0; j < 8; j++) {
    int o = o0 + j;
    int mm = o >> 4, kk = o & 15;
    out[j] = GRs[mm * 4 + 0] * GRs[kk * 4 + 0] + GRs[mm * 4 + 1] * GRs[kk * 4 + 1] +
             GRs[mm * 4 + 2] * GRs[kk * 4 + 2] + GRs[mm * 4 + 3] * GRs[kk * 4 + 3];
  }
  *(float4*)&D[atom * 2048 + o0]     = make_float4(out[0], out[1], out[2], out[3]);
  *(float4*)&D[atom * 2048 + o0 + 4] = make_float4(out[4], out[5], out[6], out[7]);
}

// ================= fitting GEMM: 64 rows x 64 cols, Kt=64 stages =================
// (round-7 exact: scalar As writes / A reads, float4 Ws, scalar acc[4][4])
template <bool GATHER, bool KSPLIT>
__global__ __launch_bounds__(256, 2) void k_fit(const float* __restrict__ Ain,
                                                const float* __restrict__ W,
                                                const float* __restrict__ bias,
                                                const int* __restrict__ cnt_type,
                                                const int* __restrict__ aidx,
                                                float* __restrict__ Out) {
  __shared__ float As[64 * 65];   // pad 65 (odd): column reads spread banks
  __shared__ float Ws[64 * 68];   // pad 68: float4-aligned row reads
  __shared__ int gidx[64];
  constexpr int KTOT = GATHER ? 2048 : 256;
  int rc = blockIdx.x, cc = blockIdx.y, z = blockIdx.z;
  int t  = KSPLIT ? (z >> 3) : z;
  int ks = KSPLIT ? (z & 7) : 0;
  int cnt = cnt_type[t];
  int r0g = rc * 64;
  if (r0g >= cnt) return;
  int m = min(64, cnt - r0g);
  int tid = threadIdx.x;
  int c0g = cc * 64;
  int k0base = ks * 256;

  if (GATHER && tid < 64)
    gidx[tid] = (r0g + tid < cnt) ? aidx[t * CAPT_ + r0g + tid] : aidx[t * CAPT_];
  __syncthreads();

  float acc[4][4] = {};
  int arow = tid >> 2, ak0 = (tid & 3) * 16;
  int rowtile = tid >> 4, coltile = tid & 15;
  int r0 = rowtile * 4, c0 = coltile * 4;

  for (int kt = 0; kt < 4; kt++) {
    int k0 = k0base + kt * 64;
    const float* ap;
    if (GATHER) ap = Ain + gidx[arow] * DIN_ + k0 + ak0;
    else        ap = Ain + (t * CAPT_ + r0g + arow) * 256 + k0 + ak0;
#pragma unroll
    for (int i = 0; i < 4; i++) {
      float4 v = ((const float4*)ap)[i];
      As[arow * 65 + ak0 + 4 * i + 0] = v.x;
      As[arow * 65 + ak0 + 4 * i + 1] = v.y;
      As[arow * 65 + ak0 + 4 * i + 2] = v.z;
      As[arow * 65 + ak0 + 4 * i + 3] = v.w;
    }
    int wk = tid >> 2, wc0 = (tid & 3) * 16;
    const float* wp = W + (t * KTOT + k0 + wk) * 256 + c0g + wc0;
#pragma unroll
    for (int i = 0; i < 4; i++)
      *(float4*)&Ws[wk * 68 + wc0 + 4 * i] = ((const float4*)wp)[i];
    __syncthreads();
#pragma unroll 4
    for (int k = 0; k < 64; k++) {
      float a[4];
#pragma unroll
      for (int i = 0; i < 4; i++) a[i] = As[(r0 + i) * 65 + k];
      float4 bb = *(const float4*)&Ws[k * 68 + c0];
#pragma unroll
      for (int i = 0; i < 4; i++) {
        acc[i][0] += a[i] * bb.x; acc[i][1] += a[i] * bb.y;
        acc[i][2] += a[i] * bb.z; acc[i][3] += a[i] * bb.w;
      }
    }
    __syncthreads();
  }
#pragma unroll
  for (int i = 0; i < 4; i++) {
    int r = r0 + i;
    if (r < m) {
      int row = t * CAPT_ + r0g + r;
      if (KSPLIT) {
        *(float4*)&Out[(ks * NROW_ + row) * 256 + c0g + c0] =
            make_float4(acc[i][0], acc[i][1], acc[i][2], acc[i][3]);
      } else {
        float4 o;
        o.x = tanh_fast(acc[i][0] + bias[t * 256 + c0g + c0 + 0]);
        o.y = tanh_fast(acc[i][1] + bias[t * 256 + c0g + c0 + 1]);
        o.z = tanh_fast(acc[i][2] + bias[t * 256 + c0g + c0 + 2]);
        o.w = tanh_fast(acc[i][3] + bias[t * 256 + c0g + c0 + 3]);
        *(float4*)&Out[row * 256 + c0g + c0] = o;
      }
    }
  }
}

// ================= layer0 K-split reduce + bias + tanh ===========================
__global__ void k_fit0_reduce(const float* __restrict__ Part,
                              const float* __restrict__ bg0, float* __restrict__ HA) {
  int idx = blockIdx.x * 256 + threadIdx.x;   // over NROW_*256
  int row = idx >> 8;
  int t = row / CAPT_;
  int c = idx & 255;
  float s = 0.f;
#pragma unroll
  for (int ks = 0; ks < 8; ks++) s += Part[ks * (NROW_ * 256) + idx];
  HA[idx] = tanh_fast(s + bg0[t * 256 + c]);
}

// ================= output layer + per-batch energy sum ===========================
__global__ void k_out(const float* __restrict__ HA, const float* __restrict__ Wgo,
                      const float* __restrict__ bgo, const int* __restrict__ cnt_type,
                      const int* __restrict__ aidx, float* __restrict__ out) {
  __shared__ float red[64][4];
  __shared__ float eb[B_];
  int rc = blockIdx.x, t = blockIdx.y;
  int cnt = cnt_type[t];
  int r0g = rc * 64;
  int tid = threadIdx.x;
  if (tid < B_) eb[tid] = 0.f;
  __syncthreads();
  int m = cnt - r0g;
  int r = tid >> 2, part = tid & 3;
  float acc = 0.f;
  if (m > 0 && r < m) {
    const float* hp = HA + (t * CAPT_ + r0g + r) * 256 + part * 64;
    const float* wp = Wgo + t * 256 + part * 64;
#pragma unroll 8
    for (int c = 0; c < 64; c++) acc += hp[c] * wp[c];
  }
  red[r][part] = acc;
  __syncthreads();
  if (part == 0 && m > 0 && r < m) {
    float e = red[r][0] + red[r][1] + red[r][2] + red[r][3] + bgo[t];
    int flat = aidx[t * CAPT_ + r0g + r];
    atomicAdd(&eb[flat >> 9], e);            // b = flat / N_
  }
  __syncthreads();
  if (tid < B_) atomicAdd(&out[tid], eb[tid]);
}

// =================================================================================
extern "C" void kernel_launch(void* const* d_in, const int* in_sizes, int n_in,
                              void* d_out, int out_size, void* d_ws, size_t ws_size,
                              hipStream_t stream) {
  // ws canary: if the workspace is too small, report its size instead of faulting
  if (ws_size < (size_t)WS_FLOATS * sizeof(float)) {
    k_canary<<<1, 1, 0, stream>>>((float*)d_out, (float)ws_size);
    return;
  }

  const float* sym  = (const float*)d_in[0];
  const float* stdv = (const float*)d_in[1];
  const float* avgv = (const float*)d_in[2];
  const int* atype  = (const int*)d_in[3];
  const int* ntype  = (const int*)d_in[4];
  const float* Wf0 = (const float*)d_in[5];
  const float* bf0 = (const float*)d_in[6];
  const float* Wf1 = (const float*)d_in[7];
  const float* bf1 = (const float*)d_in[8];
  const float* Wf2 = (const float*)d_in[9];
  const float* bf2 = (const float*)d_in[10];
  const float* Wg0 = (const float*)d_in[11];
  const float* bg0 = (const float*)d_in[12];
  const float* Wg1 = (const float*)d_in[13];
  const float* bg1 = (const float*)d_in[14];
  const float* Wg2 = (const float*)d_in[15];
  const float* bg2 = (const float*)d_in[16];
  const float* Wgo = (const float*)d_in[17];
  const float* bgo = (const float*)d_in[18];

  float* ws = (float*)d_ws;
  float* x_ws      = ws + OFF_X;
  float* s_sorted  = ws + OFF_SS;
  int*   idx_sorted= (int*)(ws + OFF_SI);
  int*   cnt_pair  = (int*)(ws + OFF_CNTP);
  int*   cnt_type  = (int*)(ws + OFF_CNTT);
  int*   aidx      = (int*)(ws + OFF_AIDX);
  int*   hist      = (int*)(ws + OFF_HIST);
  int*   base      = (int*)(ws + OFF_BASE);
  unsigned char* rank = (unsigned char*)(ws + OFF_RANK);
  float* G_ws      = ws + OFF_G;
  float* D_ws      = ws + OFF_D;
  float* Part      = ws + OFF_PART;
  float* HA        = ws + OFF_HA;
  float* HB        = ws + OFF_HB;

  k_hist<<<NBLK_, 256, 0, stream>>>(sym, stdv, avgv, atype, ntype, x_ws, hist, rank);
  k_scan<<<1, 1024, 0, stream>>>(hist, base, cnt_pair, atype, aidx, cnt_type,
                                 (float*)d_out);
  k_scatter<<<NBLK_, 256, 0, stream>>>(x_ws, atype, ntype, rank, base,
                                       s_sorted, idx_sorted);
  k_embed<<<dim3(160, 16), 256, 0, stream>>>(Wf0, bf0, Wf1, bf1, Wf2, bf2,
                                             s_sorted, idx_sorted, cnt_pair, G_ws);
  k_grd<<<NA_, 256, 0, stream>>>(G_ws, x_ws, D_ws);
  k_fit<true, true><<<dim3(6, 4, 32), 256, 0, stream>>>(D_ws, Wg0, bg0, cnt_type, aidx, Part);
  k_fit0_reduce<<<NROW_, 256, 0, stream>>>(Part, bg0, HA);
  k_fit<false, false><<<dim3(6, 4, 4), 256, 0, stream>>>(HA, Wg1, bg1, cnt_type, aidx, HB);
  k_fit<false, false><<<dim3(6, 4, 4), 256, 0, stream>>>(HB, Wg2, bg2, cnt_type, aidx, HA);
  k_out<<<dim3(6, 4), 256, 0, stream>>>(HA, Wgo, bgo, cnt_type, aidx, (float*)d_out);
}

// Round 12
// 243.479 us; speedup vs baseline: 5.6239x; 1.0612x over previous
//
#include <hip/hip_runtime.h>

// ---------------- problem constants ----------------
constexpr int B_ = 2, N_ = 512, SEL_ = 128, T_ = 4, P_ = 16;
constexpr int F2_ = 128, H_ = 256, DIN_ = 2048;
constexpr int NBT_ = B_ * N_ * SEL_;   // 131072 neighbors
constexpr int NA_  = B_ * N_;          // 1024 atoms
constexpr int NBLK_ = NBT_ / 256;      // 512 hist blocks
constexpr int CAP_  = 16384;           // per-pair sorted capacity (mean 8192, sigma ~450)
constexpr int CAPT_ = 384;             // per-type atom capacity (mean 256, sigma ~14)
constexpr int NROW_ = T_ * CAPT_;      // 1536 sorted-space fitting rows

// ---------------- workspace layout (float offsets) ----------------
constexpr int OFF_X    = 0;                       // x normalized (B,N,SEL,4)     524288
constexpr int OFF_SS   = 524288;                  // s sorted by pair             262144
constexpr int OFF_SI   = OFF_SS + P_ * CAP_;      // src idx sorted (int)         262144
constexpr int OFF_CNTP = OFF_SI + P_ * CAP_;      // pair counts (16 int)
constexpr int OFF_CNTT = OFF_CNTP + 16;           // type counts (4 int)
constexpr int OFF_AIDX = 1048608;                 // atom idx sorted by type (1536 int)
constexpr int OFF_G    = 1052672;                 // G (131072 x 128)             16777216
// ---- overlaid into the G region, phase 1 (dead once k_embed writes G) ----
constexpr int OFF_HIST = OFF_G;                   // hist   512x16 int
constexpr int OFF_BASE = OFF_G + NBLK_ * 16;      // base   512x16 int
constexpr int OFF_RANK = OFF_BASE + NBLK_ * 16;   // rank   131072 u8 (= 32768 floats)
// ---- overlaid into the G region, phase 2 (G dead after k_grd) ----
constexpr int OFF_PART = OFF_G;                   // layer0 K-split partials 8x1536x256
constexpr int OFF_HA   = OFF_G + 8 * NROW_ * H_;  // 1536x256
constexpr int OFF_HB   = OFF_HA + NROW_ * H_;     // 1536x256  (ends well inside G)
// ---- after G region ----
constexpr int OFF_D    = OFF_G + NBT_ * F2_;      // D (1024 x 2048)              2097152
constexpr int WS_FLOATS = OFF_D + NA_ * DIN_;     // 19,927,040 floats = 79.7 MB

__device__ __forceinline__ float tanh_fast(float x) {
  // 1 - 2/(e^{2x}+1): v_exp + v_rcp path, abs err ~1e-7, correct saturation at +-inf
  return 1.0f - 2.0f / (__expf(2.0f * x) + 1.0f);
}

// canary: ws too small -> report ws_size through d_out instead of faulting
__global__ void k_canary(float* out, float wsz) { out[0] = wsz; out[1] = -12345.0f; }

// ================= K1a: normalize + per-block pair histogram + stable rank =======
__global__ void k_hist(const float* __restrict__ sym, const float* __restrict__ stdv,
                       const float* __restrict__ avgv, const int* __restrict__ atype,
                       const int* __restrict__ ntype, float* __restrict__ x_ws,
                       int* __restrict__ hist, unsigned char* __restrict__ rank) {
  __shared__ int whist[4][16];                    // per-wave per-pair counts
  int tid = threadIdx.x;
  int gid = blockIdx.x * 256 + tid;
  int wave = tid >> 6, lane = tid & 63;
  unsigned long long below = (1ull << lane) - 1ull;
  if (tid < 64) whist[tid >> 4][tid & 15] = 0;
  __syncthreads();

  int at = atype[gid >> 7];                       // wave-uniform (64 | SEL)
  int nt = ntype[gid];
  float4 c = ((const float4*)sym)[gid];
  float x0 = (c.x - avgv[at * 4 + 0]) / stdv[at * 4 + 0];
  float x1 = (c.y - avgv[at * 4 + 1]) / stdv[at * 4 + 1];
  float x2 = (c.z - avgv[at * 4 + 2]) / stdv[at * 4 + 2];
  float x3 = (c.w - avgv[at * 4 + 3]) / stdv[at * 4 + 3];
  ((float4*)x_ws)[gid] = make_float4(x0, x1, x2, x3);

  int myrank = 0;
#pragma unroll
  for (int k = 0; k < 4; k++) {
    unsigned long long mk = __ballot(nt == k);
    if (lane == 0) whist[wave][at * 4 + k] = __popcll(mk);
    if (nt == k) myrank = __popcll(mk & below);
  }
  __syncthreads();
  int pair = at * 4 + nt;
  int r = myrank;
  for (int w = 0; w < wave; w++) r += whist[w][pair];
  rank[gid] = (unsigned char)r;                   // < 256 always
  if (tid < 16)
    hist[blockIdx.x * 16 + tid] =
        whist[0][tid] + whist[1][tid] + whist[2][tid] + whist[3][tid];
}

// ================= K1b: scan (1 block, 1024 thr): pair bases + atom type sort ====
__global__ void k_scan(const int* __restrict__ hist, int* __restrict__ base,
                       int* __restrict__ cnt_pair, const int* __restrict__ atype,
                       int* __restrict__ aidx, int* __restrict__ cnt_type,
                       float* __restrict__ out) {
  __shared__ int awhist[16][4];
  __shared__ int apre[16][4];
  int tid = threadIdx.x;
  int wave = tid >> 6, lane = tid & 63;           // 16 waves
  unsigned long long below = (1ull << lane) - 1ull;

  // part 1: wave p scans pair p across the 512 block histograms
  {
    int p = wave;
    int carry = 0;
    for (int rr = 0; rr < NBLK_ / 64; rr++) {
      int b = rr * 64 + lane;
      int v = hist[b * 16 + p];
      int incl = v;
#pragma unroll
      for (int d = 1; d < 64; d <<= 1) {
        int o = __shfl_up(incl, d, 64);
        if (lane >= d) incl += o;
      }
      base[b * 16 + p] = carry + incl - v;        // exclusive prefix
      carry += __shfl(incl, 63, 64);
    }
    if (lane == 0) cnt_pair[p] = carry;
  }

  // part 2: atom type sort (1024 atoms == 1024 threads)
  int at = atype[tid];
  int arank = 0;
#pragma unroll
  for (int t = 0; t < 4; t++) {
    unsigned long long mk = __ballot(at == t);
    if (lane == 0) awhist[wave][t] = __popcll(mk);
    if (at == t) arank = __popcll(mk & below);
  }
  __syncthreads();
  if (tid < 4) {                                  // thread t: prefix over 16 waves
    int s = 0;
    for (int w = 0; w < 16; w++) { apre[w][tid] = s; s += awhist[w][tid]; }
    cnt_type[tid] = s;
  }
  if (tid < B_) out[tid] = 0.0f;                  // zero d_out here
  __syncthreads();
  int pos = apre[wave][at] + arank;
  if (pos < CAPT_) aidx[at * CAPT_ + pos] = tid;
}

// ================= K1c: scatter into pair-sorted arrays ==========================
__global__ void k_scatter(const float* __restrict__ x_ws, const int* __restrict__ atype,
                          const int* __restrict__ ntype,
                          const unsigned char* __restrict__ rank,
                          const int* __restrict__ base, float* __restrict__ s_sorted,
                          int* __restrict__ idx_sorted) {
  int gid = blockIdx.x * 256 + threadIdx.x;
  int at = atype[gid >> 7];
  int nt = ntype[gid];
  int pair = at * 4 + nt;
  int pos = base[blockIdx.x * 16 + pair] + (int)rank[gid];
  float x0 = x_ws[gid * 4];
  if (pos < CAP_) {                               // defensive (never expected)
    s_sorted[pair * CAP_ + pos] = x0;
    idx_sorted[pair * CAP_ + pos] = gid;
  }
}

// ================= K2: embedding MLP 1->32->64->128 per (pair, 64-row chunk) ======
// Round-7 scalar inner loops (known-good 68us, VGPR 68) + LDS UNION: H0s/W1s (dead
// after H1 phase) share their region with the W2 half-stage. 34 KB LDS -> 4 blocks/CU
// (16 waves, was 8): attacks the measured latency-bound stall (VALUBusy 51-58%).
__global__ __launch_bounds__(256, 4) void k_embed(
    const float* __restrict__ Wf0, const float* __restrict__ bf0,
    const float* __restrict__ Wf1, const float* __restrict__ bf1,
    const float* __restrict__ Wf2, const float* __restrict__ bf2,
    const float* __restrict__ s_sorted, const int* __restrict__ idx_sorted,
    const int* __restrict__ cnt_pair, float* __restrict__ G) {
  __shared__ float smem[8704];                 // 34 KB total
  float* H1s = smem;                           // 64*65 = 4160  (live P2->P3)
  float* R2  = smem + 4160;                    // 4160-float union region:
  float* H0s = R2;                             //   P1/P2: H0s 64*33 = 2112
  float* W1s = R2 + 2112;                      //   P2:    W1s 2048 (ends 4160)
  float* W2s = R2;                             //   P3:    W2s 32*128 = 4096 (aliases H0s+W1s)
  float* ss  = smem + 8320;                    // 64
  int*   idxs= (int*)(smem + 8384);            // 64
  float* W0s = smem + 8448;                    // 32
  float* b0s = smem + 8480;                    // 32
  float* b1s = smem + 8512;                    // 64
  float* b2s = smem + 8576;                    // 128 -> 8704

  int p = blockIdx.y;
  int cnt = cnt_pair[p];
  int r0g = blockIdx.x * 64;
  if (r0g >= cnt) return;
  int m = min(64, cnt - r0g);
  int tid = threadIdx.x;

  // stage smalls + W1 (W1 region disjoint from H0s, both written before P2 sync)
  if (tid < 32) { W0s[tid] = Wf0[p * 32 + tid]; b0s[tid] = bf0[p * 32 + tid]; }
  else if (tid < 96)  b1s[tid - 32] = bf1[p * 64 + tid - 32];
  else if (tid < 224) b2s[tid - 96] = bf2[p * 128 + tid - 96];
  if (tid < 64) {
    ss[tid]   = s_sorted[p * CAP_ + r0g + tid];
    idxs[tid] = idx_sorted[p * CAP_ + r0g + tid];
  }
  for (int i = tid; i < 512; i += 256)
    ((float4*)W1s)[i] = ((const float4*)(Wf1 + p * 2048))[i];
  __syncthreads();

  // P1: H0 = tanh(s*W0+b0): 64x32, 8 outputs/thread
  {
    int row = tid >> 2, j0 = (tid & 3) * 8;
    float s = ss[row];
#pragma unroll
    for (int j = 0; j < 8; j++)
      H0s[row * 33 + j0 + j] = tanh_fast(s * W0s[j0 + j] + b0s[j0 + j]);
  }
  __syncthreads();

  int rowtile = tid >> 4, coltile = tid & 15;
  int r0 = rowtile * 4;

  // P2: H1 = tanh(H0 @ W1 + b1): 64x64, 4x4 tiles
  {
    int c0 = coltile * 4;
    float acc[4][4] = {};
#pragma unroll 4
    for (int k = 0; k < 32; k++) {
      float a[4];
#pragma unroll
      for (int i = 0; i < 4; i++) a[i] = H0s[(r0 + i) * 33 + k];
      float4 bb = *(const float4*)&W1s[k * 64 + c0];
#pragma unroll
      for (int i = 0; i < 4; i++) {
        acc[i][0] += a[i] * bb.x; acc[i][1] += a[i] * bb.y;
        acc[i][2] += a[i] * bb.z; acc[i][3] += a[i] * bb.w;
      }
    }
#pragma unroll
    for (int i = 0; i < 4; i++)
#pragma unroll
      for (int j = 0; j < 4; j++)
        H1s[(r0 + i) * 65 + c0 + j] = tanh_fast(acc[i][j] + b1s[c0 + j]);
  }
  __syncthreads();   // H0s/W1s now dead -> region becomes W2s

  // P3: G = tanh(H1 @ W2 + b2): 64x128, 4x8 tiles; W2 staged 32 k-rows per half
  {
    int c0 = coltile * 8;
    float acc[4][8] = {};
#pragma unroll
    for (int half = 0; half < 2; half++) {
      for (int i = tid; i < 1024; i += 256)
        ((float4*)W2s)[i] = ((const float4*)(Wf2 + p * 8192 + half * 4096))[i];
      __syncthreads();
#pragma unroll 4
      for (int kk = 0; kk < 32; kk++) {
        int k = half * 32 + kk;
        float a[4];
#pragma unroll
        for (int i = 0; i < 4; i++) a[i] = H1s[(r0 + i) * 65 + k];
        float4 bA = *(const float4*)&W2s[kk * 128 + c0];
        float4 bB = *(const float4*)&W2s[kk * 128 + c0 + 4];
#pragma unroll
        for (int i = 0; i < 4; i++) {
          acc[i][0] += a[i] * bA.x; acc[i][1] += a[i] * bA.y;
          acc[i][2] += a[i] * bA.z; acc[i][3] += a[i] * bA.w;
          acc[i][4] += a[i] * bB.x; acc[i][5] += a[i] * bB.y;
          acc[i][6] += a[i] * bB.z; acc[i][7] += a[i] * bB.w;
        }
      }
      __syncthreads();
    }
#pragma unroll
    for (int i = 0; i < 4; i++) {
      int r = r0 + i;
      if (r < m) {
        float4 o0, o1;
        o0.x = tanh_fast(acc[i][0] + b2s[c0 + 0]);
        o0.y = tanh_fast(acc[i][1] + b2s[c0 + 1]);
        o0.z = tanh_fast(acc[i][2] + b2s[c0 + 2]);
        o0.w = tanh_fast(acc[i][3] + b2s[c0 + 3]);
        o1.x = tanh_fast(acc[i][4] + b2s[c0 + 4]);
        o1.y = tanh_fast(acc[i][5] + b2s[c0 + 5]);
        o1.z = tanh_fast(acc[i][6] + b2s[c0 + 6]);
        o1.w = tanh_fast(acc[i][7] + b2s[c0 + 7]);
        int grow = idxs[r] * 128;
        *(float4*)&G[grow + c0]     = o0;
        *(float4*)&G[grow + c0 + 4] = o1;
      }
    }
  }
}

// ================= K3: per-atom GR = G^T x / S, D = GR @ GR[:16]^T ================
// Two 64-neighbor passes; GR accumulated in registers. (round-7 exact)
__global__ void k_grd(const float* __restrict__ G, const float* __restrict__ x_ws,
                      float* __restrict__ D) {
  __shared__ float Gs[64 * 132];
  __shared__ float xs[64 * 4];
  __shared__ float GRs[512];
  int atom = blockIdx.x;
  int tid = threadIdx.x;
  int m0 = tid >> 2,         d0v = tid & 3;
  int m1 = 64 + (tid >> 2),  d1v = d0v;
  float acc0 = 0.f, acc1 = 0.f;
#pragma unroll
  for (int pass = 0; pass < 2; pass++) {
    for (int i = tid; i < 2048; i += 256) {
      int row = i >> 5, q = i & 31;
      float4 v = ((const float4*)G)[atom * 4096 + pass * 2048 + i];
      *(float4*)&Gs[row * 132 + q * 4] = v;
    }
    if (tid < 64) *(float4*)&xs[tid * 4] = ((const float4*)x_ws)[atom * 128 + pass * 64 + tid];
    __syncthreads();
#pragma unroll 8
    for (int s = 0; s < 64; s++) {
      acc0 += Gs[s * 132 + m0] * xs[s * 4 + d0v];
      acc1 += Gs[s * 132 + m1] * xs[s * 4 + d1v];
    }
    __syncthreads();
  }
  GRs[tid]       = acc0 * (1.0f / 128.0f);
  GRs[tid + 256] = acc1 * (1.0f / 128.0f);
  __syncthreads();
  int o0 = tid * 8;
  float out[8];
#pragma unroll
  for (int j = 0; j < 8; j++) {
    int o = o0 + j;
    int mm = o >> 4, kk = o & 15;
    out[j] = GRs[mm * 4 + 0] * GRs[kk * 4 + 0] + GRs[mm * 4 + 1] * GRs[kk * 4 + 1] +
             GRs[mm * 4 + 2] * GRs[kk * 4 + 2] + GRs[mm * 4 + 3] * GRs[kk * 4 + 3];
  }
  *(float4*)&D[atom * 2048 + o0]     = make_float4(out[0], out[1], out[2], out[3]);
  *(float4*)&D[atom * 2048 + o0 + 4] = make_float4(out[4], out[5], out[6], out[7]);
}

// ================= fitting GEMM: 64 rows x 64 cols, Kt=64 stages =================
// (round-7 exact: scalar As writes / A reads, float4 Ws, scalar acc[4][4])
template <bool GATHER, bool KSPLIT>
__global__ __launch_bounds__(256, 2) void k_fit(const float* __restrict__ Ain,
                                                const float* __restrict__ W,
                                                const float* __restrict__ bias,
                                                const int* __restrict__ cnt_type,
                                                const int* __restrict__ aidx,
                                                float* __restrict__ Out) {
  __shared__ float As[64 * 65];   // pad 65 (odd): column reads spread banks
  __shared__ float Ws[64 * 68];   // pad 68: float4-aligned row reads
  __shared__ int gidx[64];
  constexpr int KTOT = GATHER ? 2048 : 256;
  int rc = blockIdx.x, cc = blockIdx.y, z = blockIdx.z;
  int t  = KSPLIT ? (z >> 3) : z;
  int ks = KSPLIT ? (z & 7) : 0;
  int cnt = cnt_type[t];
  int r0g = rc * 64;
  if (r0g >= cnt) return;
  int m = min(64, cnt - r0g);
  int tid = threadIdx.x;
  int c0g = cc * 64;
  int k0base = ks * 256;

  if (GATHER && tid < 64)
    gidx[tid] = (r0g + tid < cnt) ? aidx[t * CAPT_ + r0g + tid] : aidx[t * CAPT_];
  __syncthreads();

  float acc[4][4] = {};
  int arow = tid >> 2, ak0 = (tid & 3) * 16;
  int rowtile = tid >> 4, coltile = tid & 15;
  int r0 = rowtile * 4, c0 = coltile * 4;

  for (int kt = 0; kt < 4; kt++) {
    int k0 = k0base + kt * 64;
    const float* ap;
    if (GATHER) ap = Ain + gidx[arow] * DIN_ + k0 + ak0;
    else        ap = Ain + (t * CAPT_ + r0g + arow) * 256 + k0 + ak0;
#pragma unroll
    for (int i = 0; i < 4; i++) {
      float4 v = ((const float4*)ap)[i];
      As[arow * 65 + ak0 + 4 * i + 0] = v.x;
      As[arow * 65 + ak0 + 4 * i + 1] = v.y;
      As[arow * 65 + ak0 + 4 * i + 2] = v.z;
      As[arow * 65 + ak0 + 4 * i + 3] = v.w;
    }
    int wk = tid >> 2, wc0 = (tid & 3) * 16;
    const float* wp = W + (t * KTOT + k0 + wk) * 256 + c0g + wc0;
#pragma unroll
    for (int i = 0; i < 4; i++)
      *(float4*)&Ws[wk * 68 + wc0 + 4 * i] = ((const float4*)wp)[i];
    __syncthreads();
#pragma unroll 4
    for (int k = 0; k < 64; k++) {
      float a[4];
#pragma unroll
      for (int i = 0; i < 4; i++) a[i] = As[(r0 + i) * 65 + k];
      float4 bb = *(const float4*)&Ws[k * 68 + c0];
#pragma unroll
      for (int i = 0; i < 4; i++) {
        acc[i][0] += a[i] * bb.x; acc[i][1] += a[i] * bb.y;
        acc[i][2] += a[i] * bb.z; acc[i][3] += a[i] * bb.w;
      }
    }
    __syncthreads();
  }
#pragma unroll
  for (int i = 0; i < 4; i++) {
    int r = r0 + i;
    if (r < m) {
      int row = t * CAPT_ + r0g + r;
      if (KSPLIT) {
        *(float4*)&Out[(ks * NROW_ + row) * 256 + c0g + c0] =
            make_float4(acc[i][0], acc[i][1], acc[i][2], acc[i][3]);
      } else {
        float4 o;
        o.x = tanh_fast(acc[i][0] + bias[t * 256 + c0g + c0 + 0]);
        o.y = tanh_fast(acc[i][1] + bias[t * 256 + c0g + c0 + 1]);
        o.z = tanh_fast(acc[i][2] + bias[t * 256 + c0g + c0 + 2]);
        o.w = tanh_fast(acc[i][3] + bias[t * 256 + c0g + c0 + 3]);
        *(float4*)&Out[row * 256 + c0g + c0] = o;
      }
    }
  }
}

// ================= layer0 K-split reduce + bias + tanh ===========================
__global__ void k_fit0_reduce(const float* __restrict__ Part,
                              const float* __restrict__ bg0, float* __restrict__ HA) {
  int idx = blockIdx.x * 256 + threadIdx.x;   // over NROW_*256
  int row = idx >> 8;
  int t = row / CAPT_;
  int c = idx & 255;
  float s = 0.f;
#pragma unroll
  for (int ks = 0; ks < 8; ks++) s += Part[ks * (NROW_ * 256) + idx];
  HA[idx] = tanh_fast(s + bg0[t * 256 + c]);
}

// ================= output layer + per-batch energy sum ===========================
__global__ void k_out(const float* __restrict__ HA, const float* __restrict__ Wgo,
                      const float* __restrict__ bgo, const int* __restrict__ cnt_type,
                      const int* __restrict__ aidx, float* __restrict__ out) {
  __shared__ float red[64][4];
  __shared__ float eb[B_];
  int rc = blockIdx.x, t = blockIdx.y;
  int cnt = cnt_type[t];
  int r0g = rc * 64;
  int tid = threadIdx.x;
  if (tid < B_) eb[tid] = 0.f;
  __syncthreads();
  int m = cnt - r0g;
  int r = tid >> 2, part = tid & 3;
  float acc = 0.f;
  if (m > 0 && r < m) {
    const float* hp = HA + (t * CAPT_ + r0g + r) * 256 + part * 64;
    const float* wp = Wgo + t * 256 + part * 64;
#pragma unroll 8
    for (int c = 0; c < 64; c++) acc += hp[c] * wp[c];
  }
  red[r][part] = acc;
  __syncthreads();
  if (part == 0 && m > 0 && r < m) {
    float e = red[r][0] + red[r][1] + red[r][2] + red[r][3] + bgo[t];
    int flat = aidx[t * CAPT_ + r0g + r];
    atomicAdd(&eb[flat >> 9], e);            // b = flat / N_
  }
  __syncthreads();
  if (tid < B_) atomicAdd(&out[tid], eb[tid]);
}

// =================================================================================
extern "C" void kernel_launch(void* const* d_in, const int* in_sizes, int n_in,
                              void* d_out, int out_size, void* d_ws, size_t ws_size,
                              hipStream_t stream) {
  // ws canary: if the workspace is too small, report its size instead of faulting
  if (ws_size < (size_t)WS_FLOATS * sizeof(float)) {
    k_canary<<<1, 1, 0, stream>>>((float*)d_out, (float)ws_size);
    return;
  }

  const float* sym  = (const float*)d_in[0];
  const float* stdv = (const float*)d_in[1];
  const float* avgv = (const float*)d_in[2];
  const int* atype  = (const int*)d_in[3];
  const int* ntype  = (const int*)d_in[4];
  const float* Wf0 = (const float*)d_in[5];
  const float* bf0 = (const float*)d_in[6];
  const float* Wf1 = (const float*)d_in[7];
  const float* bf1 = (const float*)d_in[8];
  const float* Wf2 = (const float*)d_in[9];
  const float* bf2 = (const float*)d_in[10];
  const float* Wg0 = (const float*)d_in[11];
  const float* bg0 = (const float*)d_in[12];
  const float* Wg1 = (const float*)d_in[13];
  const float* bg1 = (const float*)d_in[14];
  const float* Wg2 = (const float*)d_in[15];
  const float* bg2 = (const float*)d_in[16];
  const float* Wgo = (const float*)d_in[17];
  const float* bgo = (const float*)d_in[18];

  float* ws = (float*)d_ws;
  float* x_ws      = ws + OFF_X;
  float* s_sorted  = ws + OFF_SS;
  int*   idx_sorted= (int*)(ws + OFF_SI);
  int*   cnt_pair  = (int*)(ws + OFF_CNTP);
  int*   cnt_type  = (int*)(ws + OFF_CNTT);
  int*   aidx      = (int*)(ws + OFF_AIDX);
  int*   hist      = (int*)(ws + OFF_HIST);
  int*   base      = (int*)(ws + OFF_BASE);
  unsigned char* rank = (unsigned char*)(ws + OFF_RANK);
  float* G_ws      = ws + OFF_G;
  float* D_ws      = ws + OFF_D;
  float* Part      = ws + OFF_PART;
  float* HA        = ws + OFF_HA;
  float* HB        = ws + OFF_HB;

  k_hist<<<NBLK_, 256, 0, stream>>>(sym, stdv, avgv, atype, ntype, x_ws, hist, rank);
  k_scan<<<1, 1024, 0, stream>>>(hist, base, cnt_pair, atype, aidx, cnt_type,
                                 (float*)d_out);
  k_scatter<<<NBLK_, 256, 0, stream>>>(x_ws, atype, ntype, rank, base,
                                       s_sorted, idx_sorted);
  k_embed<<<dim3(160, 16), 256, 0, stream>>>(Wf0, bf0, Wf1, bf1, Wf2, bf2,
                                             s_sorted, idx_sorted, cnt_pair, G_ws);
  k_grd<<<NA_, 256, 0, stream>>>(G_ws, x_ws, D_ws);
  k_fit<true, true><<<dim3(6, 4, 32), 256, 0, stream>>>(D_ws, Wg0, bg0, cnt_type, aidx, Part);
  k_fit0_reduce<<<NROW_, 256, 0, stream>>>(Part, bg0, HA);
  k_fit<false, false><<<dim3(6, 4, 4), 256, 0, stream>>>(HA, Wg1, bg1, cnt_type, aidx, HB);
  k_fit<false, false><<<dim3(6, 4, 4), 256, 0, stream>>>(HB, Wg2, bg2, cnt_type, aidx, HA);
  k_out<<<dim3(6, 4), 256, 0, stream>>>(HA, Wgo, bgo, cnt_type, aidx, (float*)d_out);
}